// Round 1
// baseline (1051.714 us; speedup 1.0000x reference)
//
#include <hip/hip_runtime.h>
#include <math.h>

// ---------------------------------------------------------------------------
// MinGRU, 2 layers. B=8, S=4096, D=512, H=512. fp32 throughout this round.
//
// Per layer:
//   gh = inp @ w^T + b            (GEMM: M=32768, N=1024, K=512, A,W K-major)
//   gate = gh[:, :512], hidden = gh[:, 512:]
//   h_t = c_t * h_{t-1} + z_t * g_t,  h_{-1} = 0.5
//     z = sigmoid(gate), c = sigmoid(-gate) = 1-z,
//     g(x) = x>=0 ? x+0.5 : sigmoid(x)
//   (exactly equivalent to the reference's log-domain cumlogsumexp scan)
//
// Scan parallelized as chunked 2-level scan: 64 chunks of 64 steps.
// ---------------------------------------------------------------------------

#define TM 128
#define TN 128
#define BK 16
#define LDSP (TM + 4)   // +4 pad: staggers banks, keeps float4 alignment

__global__ __launch_bounds__(256) void gemm_nt_bias(
    const float* __restrict__ A,    // M x K row-major
    const float* __restrict__ W,    // N x K row-major
    const float* __restrict__ bias, // N
    float* __restrict__ C,          // M x N
    int M, int N, int K)
{
    __shared__ float As[BK][LDSP];
    __shared__ float Ws[BK][LDSP];
    const int tid = threadIdx.x;
    const int bm = blockIdx.y;
    const int bn = blockIdx.x;

    // staging: each thread loads 8 contiguous floats (2 float4) of one row
    const int srow  = tid >> 1;        // 0..127 tile row
    const int skoff = (tid & 1) * 8;   // 0 or 8 within BK=16

    const float* Ap = A + (size_t)(bm * TM + srow) * K + skoff;
    const float* Wp = W + (size_t)(bn * TN + srow) * K + skoff;

    const int tx = tid & 15;   // n micro-tile
    const int ty = tid >> 4;   // m micro-tile

    float acc[8][8];
    #pragma unroll
    for (int i = 0; i < 8; ++i)
        #pragma unroll
        for (int j = 0; j < 8; ++j) acc[i][j] = 0.f;

    for (int k0 = 0; k0 < K; k0 += BK) {
        float4 a0 = *(const float4*)(Ap);
        float4 a1 = *(const float4*)(Ap + 4);
        float4 w0 = *(const float4*)(Wp);
        float4 w1 = *(const float4*)(Wp + 4);
        __syncthreads();   // previous compute phase done before overwrite
        As[skoff + 0][srow] = a0.x; As[skoff + 1][srow] = a0.y;
        As[skoff + 2][srow] = a0.z; As[skoff + 3][srow] = a0.w;
        As[skoff + 4][srow] = a1.x; As[skoff + 5][srow] = a1.y;
        As[skoff + 6][srow] = a1.z; As[skoff + 7][srow] = a1.w;
        Ws[skoff + 0][srow] = w0.x; Ws[skoff + 1][srow] = w0.y;
        Ws[skoff + 2][srow] = w0.z; Ws[skoff + 3][srow] = w0.w;
        Ws[skoff + 4][srow] = w1.x; Ws[skoff + 5][srow] = w1.y;
        Ws[skoff + 6][srow] = w1.z; Ws[skoff + 7][srow] = w1.w;
        __syncthreads();
        #pragma unroll
        for (int k = 0; k < BK; ++k) {
            float4 av0 = *(const float4*)&As[k][ty * 8];
            float4 av1 = *(const float4*)&As[k][ty * 8 + 4];
            float4 wv0 = *(const float4*)&Ws[k][tx * 8];
            float4 wv1 = *(const float4*)&Ws[k][tx * 8 + 4];
            float a[8] = {av0.x, av0.y, av0.z, av0.w, av1.x, av1.y, av1.z, av1.w};
            float b[8] = {wv0.x, wv0.y, wv0.z, wv0.w, wv1.x, wv1.y, wv1.z, wv1.w};
            #pragma unroll
            for (int i = 0; i < 8; ++i)
                #pragma unroll
                for (int j = 0; j < 8; ++j)
                    acc[i][j] = fmaf(a[i], b[j], acc[i][j]);
        }
        Ap += BK; Wp += BK;
    }

    float4 bv0 = *(const float4*)(bias + bn * TN + tx * 8);
    float4 bv1 = *(const float4*)(bias + bn * TN + tx * 8 + 4);
    const float bb[8] = {bv0.x, bv0.y, bv0.z, bv0.w, bv1.x, bv1.y, bv1.z, bv1.w};
    #pragma unroll
    for (int i = 0; i < 8; ++i) {
        const int row = bm * TM + ty * 8 + i;
        float* cp = C + (size_t)row * N + bn * TN + tx * 8;
        float4 o0 = {acc[i][0] + bb[0], acc[i][1] + bb[1], acc[i][2] + bb[2], acc[i][3] + bb[3]};
        float4 o1 = {acc[i][4] + bb[4], acc[i][5] + bb[5], acc[i][6] + bb[6], acc[i][7] + bb[7]};
        *(float4*)(cp)     = o0;
        *(float4*)(cp + 4) = o1;
    }
}

// ---------------------------------------------------------------------------
// Scan helpers. H=512 hardcoded, gh row width = 1024.
// ---------------------------------------------------------------------------
__device__ __forceinline__ void coeff_val(float gate, float hid, float& c, float& v)
{
    // stable sigmoid pair: z = sigmoid(gate), c = sigmoid(-gate)
    float eg  = __expf(-fabsf(gate));
    float inv = 1.0f / (1.0f + eg);
    float sp  = inv;        // sigmoid(|gate|)
    float sn  = eg * inv;   // sigmoid(-|gate|)
    float z   = (gate >= 0.f) ? sp : sn;
    c         = (gate >= 0.f) ? sn : sp;
    float eh  = __expf(-fabsf(hid));
    float gneg = eh / (1.0f + eh);          // sigmoid(hid) for hid<0
    float g   = (hid >= 0.f) ? (hid + 0.5f) : gneg;
    v = z * g;
}

// Pass 1: per (b, chunk, h): chunk transfer A = prod c, V = chunk applied to 0
__global__ __launch_bounds__(256) void scan_pass1(
    const float* __restrict__ gh, float* __restrict__ cA, float* __restrict__ cV,
    int S, int Lc, int Nc)
{
    const int tid = threadIdx.x;
    const int b  = blockIdx.x / Nc;
    const int ck = blockIdx.x % Nc;
    const int h  = blockIdx.y * 256 + tid;   // 0..511
    const float* base = gh + (size_t)(b * S + ck * Lc) * 1024;
    float Aacc = 1.f, Vacc = 0.f;
    for (int s = 0; s < Lc; ++s) {
        float gate = base[(size_t)s * 1024 + h];
        float hid  = base[(size_t)s * 1024 + 512 + h];
        float c, v; coeff_val(gate, hid, c, v);
        Aacc *= c;
        Vacc = fmaf(c, Vacc, v);
    }
    const size_t idx = (size_t)(b * Nc + ck) * 512 + h;
    cA[idx] = Aacc;
    cV[idx] = Vacc;
}

// Pass 2: sequential combine across chunks; carry[b][ck][h] = h-state entering chunk ck
__global__ __launch_bounds__(256) void scan_pass2(
    const float* __restrict__ cA, const float* __restrict__ cV,
    float* __restrict__ carry, int Nc)
{
    const int tid = threadIdx.x;
    const int b = blockIdx.x >> 1;
    const int h = (blockIdx.x & 1) * 256 + tid;
    float state = 0.5f;   // h0
    for (int ck = 0; ck < Nc; ++ck) {
        const size_t idx = (size_t)(b * Nc + ck) * 512 + h;
        carry[idx] = state;
        state = fmaf(cA[idx], state, cV[idx]);
    }
}

// Pass 3: replay each chunk from its carry, writing all h_t (and last-step h)
__global__ __launch_bounds__(256) void scan_pass3(
    const float* __restrict__ gh, const float* __restrict__ carry,
    float* __restrict__ out, float* __restrict__ nh,
    int S, int Lc, int Nc)
{
    const int tid = threadIdx.x;
    const int b  = blockIdx.x / Nc;
    const int ck = blockIdx.x % Nc;
    const int h  = blockIdx.y * 256 + tid;
    const float* base = gh + (size_t)(b * S + ck * Lc) * 1024;
    float hst = carry[(size_t)(b * Nc + ck) * 512 + h];
    float* obase = out + (size_t)(b * S + ck * Lc) * 512;
    for (int s = 0; s < Lc; ++s) {
        float gate = base[(size_t)s * 1024 + h];
        float hid  = base[(size_t)s * 1024 + 512 + h];
        float c, v; coeff_val(gate, hid, c, v);
        hst = fmaf(c, hst, v);
        obase[(size_t)s * 512 + h] = hst;
    }
    if (ck == Nc - 1) {
        nh[(size_t)b * 512 + h] = hst;   // h at s = S-1
    }
}

extern "C" void kernel_launch(void* const* d_in, const int* in_sizes, int n_in,
                              void* d_out, int out_size, void* d_ws, size_t ws_size,
                              hipStream_t stream)
{
    const float* x  = (const float*)d_in[0];
    const float* w0 = (const float*)d_in[1];
    const float* b0 = (const float*)d_in[2];
    const float* w1 = (const float*)d_in[3];
    const float* b1 = (const float*)d_in[4];
    float* out = (float*)d_out;

    const int B = 8, S = 4096, K = 512, N = 1024;
    const int M = B * S;            // 32768
    const int Lc = 64, Nc = S / Lc; // 64 chunks of 64

    // workspace layout (floats): gh (M*N, reused both layers), h0out (M*512),
    // cA/cV/carry (B*Nc*512 each). Total ~195 MiB.
    float* ws    = (float*)d_ws;
    float* gh    = ws;
    float* h0out = gh + (size_t)M * N;
    float* cA    = h0out + (size_t)M * 512;
    float* cV    = cA + (size_t)B * Nc * 512;
    float* carry = cV + (size_t)B * Nc * 512;

    dim3 ggrid(N / TN, M / TM);          // 8 x 256
    dim3 sgrid(B * Nc, 2);               // 512 x 2
    dim3 blk(256);

    float* nh0 = out + (size_t)M * 512;             // next_hidden layer 0
    float* nh1 = nh0 + (size_t)B * 512;             // next_hidden layer 1

    // ---- layer 0 ----
    gemm_nt_bias<<<ggrid, blk, 0, stream>>>(x, w0, b0, gh, M, N, K);
    scan_pass1<<<sgrid, blk, 0, stream>>>(gh, cA, cV, S, Lc, Nc);
    scan_pass2<<<dim3(B * 2), blk, 0, stream>>>(cA, cV, carry, Nc);
    scan_pass3<<<sgrid, blk, 0, stream>>>(gh, carry, h0out, nh0, S, Lc, Nc);

    // ---- layer 1 ----
    gemm_nt_bias<<<ggrid, blk, 0, stream>>>(h0out, w1, b1, gh, M, N, K);
    scan_pass1<<<sgrid, blk, 0, stream>>>(gh, cA, cV, S, Lc, Nc);
    scan_pass2<<<dim3(B * 2), blk, 0, stream>>>(cA, cV, carry, Nc);
    scan_pass3<<<sgrid, blk, 0, stream>>>(gh, carry, out, nh1, S, Lc, Nc);
}

// Round 2
// 381.811 us; speedup vs baseline: 2.7545x; 2.7545x over previous
//
#include <hip/hip_runtime.h>
#include <math.h>

// ---------------------------------------------------------------------------
// MinGRU, 2 layers. B=8, S=4096, D=H=512.
// Round 2: bf16 MFMA GEMM (m97-style: 128x128 tile, BK=32, 16x16x32 MFMA,
// global_load_lds width=16, XOR-swizzled quarters), gh stored bf16.
// Scan: chunked 2-level scan, 64 chunks x 64 steps, 2 channels/thread.
// ---------------------------------------------------------------------------

typedef unsigned short ushort_t;
typedef __attribute__((ext_vector_type(8))) short short8;   // 8 bf16 = 4 VGPR
typedef __attribute__((ext_vector_type(4))) float f32x4;

__device__ __forceinline__ ushort_t f2bf(float f) {
    unsigned int u = __float_as_uint(f);
    unsigned int r = (u + 0x7fffu + ((u >> 16) & 1u)) >> 16;   // RNE
    return (ushort_t)r;
}
__device__ __forceinline__ float bf2f(ushort_t u) {
    return __uint_as_float(((unsigned int)u) << 16);
}

__device__ __forceinline__ void async16(const void* g, void* l) {
    __builtin_amdgcn_global_load_lds(
        (const __attribute__((address_space(1))) unsigned int*)g,
        (__attribute__((address_space(3))) unsigned int*)l, 16, 0, 0);
}

// ---------------------------------------------------------------------------
// fp32 -> bf16 cast, 4 elements/thread
// ---------------------------------------------------------------------------
__global__ __launch_bounds__(256) void cvt_f32_bf16(
    const float* __restrict__ in, ushort_t* __restrict__ out, int n4)
{
    int i = blockIdx.x * 256 + threadIdx.x;
    if (i >= n4) return;
    float4 v = ((const float4*)in)[i];
    ushort4 o = make_ushort4(f2bf(v.x), f2bf(v.y), f2bf(v.z), f2bf(v.w));
    ((ushort4*)out)[i] = o;
}

// ---------------------------------------------------------------------------
// C = A(MxK,bf16) . W(NxK,bf16)^T + bias(fp32), C bf16.  M%128==N%128==K%32==0
// 256 threads = 4 waves; wave computes 64x64 (4x4 MFMA tiles of 16x16x32).
// ---------------------------------------------------------------------------
__global__ __launch_bounds__(256) void gemm_bf16_nt(
    const ushort_t* __restrict__ A, const ushort_t* __restrict__ W,
    const float* __restrict__ bias, ushort_t* __restrict__ C,
    int M, int N, int K)
{
    __shared__ __align__(16) ushort_t As[128 * 32];
    __shared__ __align__(16) ushort_t Ws[128 * 32];

    const int tid  = threadIdx.x;
    const int bm   = blockIdx.y;
    const int bn   = blockIdx.x;
    const int lane = tid & 63;
    const int wave = tid >> 6;
    const int wm   = (wave >> 1) * 64;
    const int wn   = (wave & 1) * 64;
    const int fm   = lane & 15;    // frag row/col within 16
    const int kb   = lane >> 4;    // k-quarter 0..3
    const int rb   = kb * 4;       // C/D row base

    // --- staging: granule g = it*256+tid covers (row=g>>2, slot q=g&3);
    //     slot q holds global quarter q ^ ((row>>1)&3)  (read-side involution)
    const int g0 = tid, g1 = tid + 256;
    const int r0 = g0 >> 2, q0 = (g0 & 3) ^ ((g0 >> 3) & 3);   // (g>>2)>>1 = g>>3
    const int r1 = g1 >> 2, q1 = (g1 & 3) ^ ((g1 >> 3) & 3);
    const ushort_t* Ap0 = A + (size_t)(bm * 128 + r0) * K + q0 * 8;
    const ushort_t* Ap1 = A + (size_t)(bm * 128 + r1) * K + q1 * 8;
    const ushort_t* Wp0 = W + (size_t)(bn * 128 + r0) * K + q0 * 8;
    const ushort_t* Wp1 = W + (size_t)(bn * 128 + r1) * K + q1 * 8;
    char* lA0 = (char*)As + g0 * 16;
    char* lA1 = (char*)As + g1 * 16;
    char* lW0 = (char*)Ws + g0 * 16;
    char* lW1 = (char*)Ws + g1 * 16;

    // --- frag read LDS byte offsets (fixed across K-iters)
    int offA[4], offB[4];
    #pragma unroll
    for (int i = 0; i < 4; ++i) {
        int rowA = wm + i * 16 + fm;
        offA[i] = rowA * 64 + ((kb ^ ((rowA >> 1) & 3)) * 16);
        int rowB = wn + i * 16 + fm;
        offB[i] = rowB * 64 + ((kb ^ ((rowB >> 1) & 3)) * 16);
    }

    f32x4 acc[4][4];
    #pragma unroll
    for (int i = 0; i < 4; ++i)
        #pragma unroll
        for (int j = 0; j < 4; ++j)
            acc[i][j] = (f32x4){0.f, 0.f, 0.f, 0.f};

    const char* AsB = (const char*)As;
    const char* WsB = (const char*)Ws;

    for (int kt = 0; kt < K; kt += 32) {
        async16(Ap0, lA0);
        async16(Ap1, lA1);
        async16(Wp0, lW0);
        async16(Wp1, lW1);
        __syncthreads();                 // drain vmcnt, LDS visible
        short8 a[4], b[4];
        #pragma unroll
        for (int i = 0; i < 4; ++i) a[i] = *(const short8*)(AsB + offA[i]);
        #pragma unroll
        for (int j = 0; j < 4; ++j) b[j] = *(const short8*)(WsB + offB[j]);
        #pragma unroll
        for (int i = 0; i < 4; ++i)
            #pragma unroll
            for (int j = 0; j < 4; ++j)
                acc[i][j] = __builtin_amdgcn_mfma_f32_16x16x32_bf16(
                    a[i], b[j], acc[i][j], 0, 0, 0);
        __syncthreads();                 // reads done before next overwrite
        Ap0 += 32; Ap1 += 32; Wp0 += 32; Wp1 += 32;
    }

    // epilogue: bias + bf16 store. C/D: col=lane&15, row=(lane>>4)*4+reg
    #pragma unroll
    for (int j = 0; j < 4; ++j) {
        const int col = bn * 128 + wn + j * 16 + fm;
        const float bv = bias[col];
        #pragma unroll
        for (int i = 0; i < 4; ++i) {
            const int row0 = bm * 128 + wm + i * 16 + rb;
            f32x4 v = acc[i][j];
            #pragma unroll
            for (int r = 0; r < 4; ++r)
                C[(size_t)(row0 + r) * N + col] = f2bf(v[r] + bv);
        }
    }
}

// ---------------------------------------------------------------------------
// Scan. gh bf16 rows of 1024: [0:512)=gate, [512:1024)=hidden.
// h_t = c*h_{t-1} + z*g(hid); z=sigmoid(gate), c=sigmoid(-gate),
// g(x)=x>=0?x+0.5:sigmoid(x). Each thread owns 2 adjacent channels.
// ---------------------------------------------------------------------------
__device__ __forceinline__ void coeff_val(float gate, float hid, float& c, float& v)
{
    float eg  = __expf(-fabsf(gate));
    float inv = 1.0f / (1.0f + eg);
    float sp  = inv;
    float sn  = eg * inv;
    float z   = (gate >= 0.f) ? sp : sn;
    c         = (gate >= 0.f) ? sn : sp;
    float eh  = __expf(-fabsf(hid));
    float gneg = eh / (1.0f + eh);
    float g   = (hid >= 0.f) ? (hid + 0.5f) : gneg;
    v = z * g;
}

__global__ __launch_bounds__(256) void scan_pass1(
    const ushort_t* __restrict__ gh, float* __restrict__ cA, float* __restrict__ cV,
    int S, int Lc, int Nc)
{
    const int tid = threadIdx.x;
    const int b  = blockIdx.x / Nc;
    const int ck = blockIdx.x % Nc;
    const ushort_t* base = gh + (size_t)(b * S + ck * Lc) * 1024 + 2 * tid;
    float A0 = 1.f, V0 = 0.f, A1 = 1.f, V1 = 0.f;
    #pragma unroll 4
    for (int s = 0; s < Lc; ++s) {
        ushort2 g2 = *(const ushort2*)(base + (size_t)s * 1024);
        ushort2 h2 = *(const ushort2*)(base + (size_t)s * 1024 + 512);
        float c0, v0, c1, v1;
        coeff_val(bf2f(g2.x), bf2f(h2.x), c0, v0);
        coeff_val(bf2f(g2.y), bf2f(h2.y), c1, v1);
        A0 *= c0; V0 = fmaf(c0, V0, v0);
        A1 *= c1; V1 = fmaf(c1, V1, v1);
    }
    const size_t idx = (size_t)(b * Nc + ck) * 512 + 2 * tid;
    *(float2*)(cA + idx) = make_float2(A0, A1);
    *(float2*)(cV + idx) = make_float2(V0, V1);
}

__global__ __launch_bounds__(256) void scan_pass2(
    const float* __restrict__ cA, const float* __restrict__ cV,
    float* __restrict__ carry, int Nc)
{
    const int tid = threadIdx.x;
    const int b = blockIdx.x;
    float s0 = 0.5f, s1 = 0.5f;   // h0
    for (int ck = 0; ck < Nc; ++ck) {
        const size_t idx = (size_t)(b * Nc + ck) * 512 + 2 * tid;
        *(float2*)(carry + idx) = make_float2(s0, s1);
        float2 a = *(const float2*)(cA + idx);
        float2 v = *(const float2*)(cV + idx);
        s0 = fmaf(a.x, s0, v.x);
        s1 = fmaf(a.y, s1, v.y);
    }
}

template <bool OUT_BF16>
__global__ __launch_bounds__(256) void scan_pass3(
    const ushort_t* __restrict__ gh, const float* __restrict__ carry,
    void* __restrict__ outv, float* __restrict__ nh,
    int S, int Lc, int Nc)
{
    const int tid = threadIdx.x;
    const int b  = blockIdx.x / Nc;
    const int ck = blockIdx.x % Nc;
    const ushort_t* base = gh + (size_t)(b * S + ck * Lc) * 1024 + 2 * tid;
    const size_t cidx = (size_t)(b * Nc + ck) * 512 + 2 * tid;
    float2 st = *(const float2*)(carry + cidx);
    float h0 = st.x, h1 = st.y;
    const size_t obase = (size_t)(b * S + ck * Lc) * 512 + 2 * tid;
    #pragma unroll 4
    for (int s = 0; s < Lc; ++s) {
        ushort2 g2 = *(const ushort2*)(base + (size_t)s * 1024);
        ushort2 h2 = *(const ushort2*)(base + (size_t)s * 1024 + 512);
        float c0, v0, c1, v1;
        coeff_val(bf2f(g2.x), bf2f(h2.x), c0, v0);
        coeff_val(bf2f(g2.y), bf2f(h2.y), c1, v1);
        h0 = fmaf(c0, h0, v0);
        h1 = fmaf(c1, h1, v1);
        if (OUT_BF16) {
            ushort2 o = make_ushort2(f2bf(h0), f2bf(h1));
            *(ushort2*)((ushort_t*)outv + obase + (size_t)s * 512) = o;
        } else {
            *(float2*)((float*)outv + obase + (size_t)s * 512) = make_float2(h0, h1);
        }
    }
    if (ck == Nc - 1)
        *(float2*)(nh + (size_t)b * 512 + 2 * tid) = make_float2(h0, h1);
}

// ---------------------------------------------------------------------------
extern "C" void kernel_launch(void* const* d_in, const int* in_sizes, int n_in,
                              void* d_out, int out_size, void* d_ws, size_t ws_size,
                              hipStream_t stream)
{
    const float* x  = (const float*)d_in[0];
    const float* w0 = (const float*)d_in[1];
    const float* b0 = (const float*)d_in[2];
    const float* w1 = (const float*)d_in[3];
    const float* b1 = (const float*)d_in[4];
    float* out = (float*)d_out;

    const int B = 8, S = 4096, K = 512, N = 1024;
    const int M = B * S;             // 32768
    const int Lc = 64, Nc = S / Lc;  // 64 chunks of 64

    // workspace (bf16 counts): gh M*1024, xb M*512, h0b M*512, w0b/w1b 1024*512
    ushort_t* gh  = (ushort_t*)d_ws;
    ushort_t* xb  = gh  + (size_t)M * 1024;
    ushort_t* h0b = xb  + (size_t)M * 512;
    ushort_t* w0b = h0b + (size_t)M * 512;
    ushort_t* w1b = w0b + (size_t)1024 * 512;
    float* cA    = (float*)(w1b + (size_t)1024 * 512);
    float* cV    = cA + (size_t)B * Nc * 512;
    float* carry = cV + (size_t)B * Nc * 512;

    float* nh0 = out + (size_t)M * 512;
    float* nh1 = nh0 + (size_t)B * 512;

    dim3 blk(256);
    dim3 ggrid(N / 128, M / 128);    // 8 x 256
    dim3 sgrid(B * Nc);              // 512

    // casts
    cvt_f32_bf16<<<dim3((M * K / 4 + 255) / 256), blk, 0, stream>>>(x, xb, M * K / 4);
    cvt_f32_bf16<<<dim3((N * K / 4 + 255) / 256), blk, 0, stream>>>(w0, w0b, N * K / 4);
    cvt_f32_bf16<<<dim3((N * K / 4 + 255) / 256), blk, 0, stream>>>(w1, w1b, N * K / 4);

    // ---- layer 0 ----
    gemm_bf16_nt<<<ggrid, blk, 0, stream>>>(xb, w0b, b0, gh, M, N, K);
    scan_pass1<<<sgrid, blk, 0, stream>>>(gh, cA, cV, S, Lc, Nc);
    scan_pass2<<<dim3(B), blk, 0, stream>>>(cA, cV, carry, Nc);
    scan_pass3<true><<<sgrid, blk, 0, stream>>>(gh, carry, h0b, nh0, S, Lc, Nc);

    // ---- layer 1 ----
    gemm_bf16_nt<<<ggrid, blk, 0, stream>>>(h0b, w1b, b1, gh, M, N, K);
    scan_pass1<<<sgrid, blk, 0, stream>>>(gh, cA, cV, S, Lc, Nc);
    scan_pass2<<<dim3(B), blk, 0, stream>>>(cA, cV, carry, Nc);
    scan_pass3<false><<<sgrid, blk, 0, stream>>>(gh, carry, out, nh1, S, Lc, Nc);
}

// Round 4
// 322.117 us; speedup vs baseline: 3.2650x; 1.1853x over previous
//
#include <hip/hip_runtime.h>
#include <math.h>

// ---------------------------------------------------------------------------
// MinGRU, 2 layers. B=8, S=4096, D=H=512.
// Round 4: round-3 structure with the grid bug fixed: 8 channel-blocks (not
// 16) — each block owns 64 channels = 128 output columns (64 gate + 64
// hidden) via W-row permutation. Fused epilogue: bias + bf16 C-tile via LDS
// (coalesced gh stores) + in-LDS chunk summaries (pass1). 7 dispatches.
// ---------------------------------------------------------------------------

typedef unsigned short u16;
typedef __attribute__((ext_vector_type(8))) short short8;   // 8 bf16 = 4 VGPR
typedef __attribute__((ext_vector_type(4))) float f32x4;

__device__ __forceinline__ u16 f2bf(float f) {
    unsigned int u = __float_as_uint(f);
    return (u16)((u + 0x7fffu + ((u >> 16) & 1u)) >> 16);   // RNE
}
__device__ __forceinline__ float bf2f(u16 u) {
    return __uint_as_float(((unsigned int)u) << 16);
}
__device__ __forceinline__ void async16(const void* g, void* l) {
    __builtin_amdgcn_global_load_lds(
        (const __attribute__((address_space(1))) unsigned int*)g,
        (__attribute__((address_space(3))) unsigned int*)l, 16, 0, 0);
}

__device__ __forceinline__ void coeff_val(float gate, float hid, float& c, float& v)
{
    float eg  = __expf(-fabsf(gate));
    float inv = 1.0f / (1.0f + eg);
    float sp  = inv;                       // sigmoid(|gate|)
    float sn  = eg * inv;                  // sigmoid(-|gate|)
    float z   = (gate >= 0.f) ? sp : sn;   // sigmoid(gate)
    c         = (gate >= 0.f) ? sn : sp;   // sigmoid(-gate)
    float eh  = __expf(-fabsf(hid));
    float gneg = eh / (1.0f + eh);
    float g   = (hid >= 0.f) ? (hid + 0.5f) : gneg;
    v = z * g;
}

// ---------------------------------------------------------------------------
// Fused cast: x (nx4 float4s) then w0, w1 (nw4 float4s each), one flat grid.
// ---------------------------------------------------------------------------
__global__ __launch_bounds__(256) void cast3(
    const float* __restrict__ x,  u16* __restrict__ xb,  int nx4,
    const float* __restrict__ w0, u16* __restrict__ w0b,
    const float* __restrict__ w1, u16* __restrict__ w1b, int nw4)
{
    int i = blockIdx.x * 256 + threadIdx.x;
    const float* src; u16* dst; int idx;
    if (i < nx4)                { src = x;  dst = xb;  idx = i; }
    else if (i < nx4 + nw4)     { src = w0; dst = w0b; idx = i - nx4; }
    else if (i < nx4 + 2 * nw4) { src = w1; dst = w1b; idx = i - nx4 - nw4; }
    else return;
    float4 v = ((const float4*)src)[idx];
    ushort4 o = make_ushort4(f2bf(v.x), f2bf(v.y), f2bf(v.z), f2bf(v.w));
    ((ushort4*)dst)[idx] = o;
}

// ---------------------------------------------------------------------------
// gemm_fused: C = A(128 rows) . Wperm^T + bias -> gh (bf16, coalesced) and
// per-chunk scan summaries cA/cV. Block = 64 channels x 128 rows (2 chunks).
// Grid: (8, M/128). N=1024, H=512, Nc=64, chunk=64 hardcoded.
// W row permutation: tile row r<64 -> gate row bn*64+r; r>=64 -> hidden row
// 512 + bn*64 + (r-64). Requires bn in [0,8).
// ---------------------------------------------------------------------------
#define TSTR 136   // epilogue C-tile row stride in ushorts (272 B, 16B-aligned)

__global__ __launch_bounds__(256) void gemm_fused(
    const u16* __restrict__ A, const u16* __restrict__ W,
    const float* __restrict__ bias, u16* __restrict__ gh,
    float* __restrict__ cA, float* __restrict__ cV, int K)
{
    __shared__ __align__(16) u16 lds[128 * TSTR];   // 34 KB; K-loop uses first 16 KB
    __shared__ float2 csum[2][2][64];               // [chunk][half][ch]

    u16* Asm = lds;          // 128*32 = 4096 ushorts (8 KB)
    u16* Wsm = lds + 4096;   // 8 KB

    const int tid  = threadIdx.x;
    const int bm   = blockIdx.y;
    const int bn   = blockIdx.x;            // 0..7: channels [bn*64, bn*64+64)
    const int lane = tid & 63;
    const int wave = tid >> 6;
    const int wm   = (wave >> 1) * 64;
    const int wn   = (wave & 1) * 64;
    const int fm   = lane & 15;
    const int kb   = lane >> 4;

    // staging granules (swizzled quarters, read-side involution)
    const int g0 = tid, g1 = tid + 256;
    const int r0 = g0 >> 2, q0 = (g0 & 3) ^ ((g0 >> 3) & 3);   // r0 in [0,64)
    const int r1 = g1 >> 2, q1 = (g1 & 3) ^ ((g1 >> 3) & 3);   // r1 in [64,128)
    const int wr0 = bn * 64 + (r0 & 63) + ((r0 >> 6) << 9);    // gate rows
    const int wr1 = bn * 64 + (r1 & 63) + ((r1 >> 6) << 9);    // hidden rows
    const u16* Ap0 = A + (size_t)(bm * 128 + r0) * K + q0 * 8;
    const u16* Ap1 = A + (size_t)(bm * 128 + r1) * K + q1 * 8;
    const u16* Wp0 = W + (size_t)wr0 * K + q0 * 8;
    const u16* Wp1 = W + (size_t)wr1 * K + q1 * 8;
    char* lA0 = (char*)Asm + g0 * 16;
    char* lA1 = (char*)Asm + g1 * 16;
    char* lW0 = (char*)Wsm + g0 * 16;
    char* lW1 = (char*)Wsm + g1 * 16;

    int offA[4], offB[4];
    #pragma unroll
    for (int i = 0; i < 4; ++i) {
        int rowA = wm + i * 16 + fm;
        offA[i] = rowA * 64 + ((kb ^ ((rowA >> 1) & 3)) * 16);
        int rowB = wn + i * 16 + fm;
        offB[i] = rowB * 64 + ((kb ^ ((rowB >> 1) & 3)) * 16);
    }

    f32x4 acc[4][4];
    #pragma unroll
    for (int i = 0; i < 4; ++i)
        #pragma unroll
        for (int j = 0; j < 4; ++j)
            acc[i][j] = (f32x4){0.f, 0.f, 0.f, 0.f};

    const char* AsB = (const char*)Asm;
    const char* WsB = (const char*)Wsm;

    for (int kt = 0; kt < K; kt += 32) {
        async16(Ap0, lA0);
        async16(Ap1, lA1);
        async16(Wp0, lW0);
        async16(Wp1, lW1);
        __syncthreads();
        short8 a[4], b[4];
        #pragma unroll
        for (int i = 0; i < 4; ++i) a[i] = *(const short8*)(AsB + offA[i]);
        #pragma unroll
        for (int j = 0; j < 4; ++j) b[j] = *(const short8*)(WsB + offB[j]);
        #pragma unroll
        for (int i = 0; i < 4; ++i)
            #pragma unroll
            for (int j = 0; j < 4; ++j)
                acc[i][j] = __builtin_amdgcn_mfma_f32_16x16x32_bf16(
                    a[i], b[j], acc[i][j], 0, 0, 0);
        __syncthreads();
        Ap0 += 32; Ap1 += 32; Wp0 += 32; Wp1 += 32;
    }

    // ---- epilogue: bias + write bf16 C-tile into LDS ----
    float bv[4];
    #pragma unroll
    for (int j = 0; j < 4; ++j) {
        int c = wn + j * 16 + fm;
        bv[j] = bias[bn * 64 + (c & 63) + ((c >> 6) << 9)];
    }
    #pragma unroll
    for (int i = 0; i < 4; ++i)
        #pragma unroll
        for (int j = 0; j < 4; ++j) {
            const int col = wn + j * 16 + fm;
            f32x4 v = acc[i][j];
            #pragma unroll
            for (int r = 0; r < 4; ++r)
                lds[(wm + i * 16 + kb * 4 + r) * TSTR + col] = f2bf(v[r] + bv[j]);
        }
    __syncthreads();

    // ---- coalesced gh store: tile col c<64 -> gate col, c>=64 -> hidden col
    #pragma unroll
    for (int it = 0; it < 8; ++it) {
        const int h   = it & 1;
        const int row = (it >> 1) * 32 + (tid >> 3);
        const int sc  = (tid & 7) * 8;
        short8 vv = *(const short8*)&lds[row * TSTR + h * 64 + sc];
        *(short8*)&gh[(size_t)(bm * 128 + row) * 1024 + h * 512 + bn * 64 + sc] = vv;
    }

    // ---- fused pass1: chunk summaries from LDS tile ----
    const int ch   = tid & 63;
    const int half = (tid >> 6) & 1;
    const int ck   = tid >> 7;            // block covers 2 chunks of 64 rows
    float Aa = 1.f, Vv = 0.f;
    const int rbase = ck * 64 + half * 32;
    #pragma unroll 4
    for (int s = 0; s < 32; ++s) {
        const int row = rbase + s;
        float gate = bf2f(lds[row * TSTR + ch]);
        float hid  = bf2f(lds[row * TSTR + 64 + ch]);
        float c, v; coeff_val(gate, hid, c, v);
        Aa *= c;
        Vv = fmaf(c, Vv, v);
    }
    csum[ck][half][ch] = make_float2(Aa, Vv);
    __syncthreads();
    if (half == 0) {
        float2 s0 = csum[ck][0][ch];     // rows [0,32) of chunk
        float2 s1 = csum[ck][1][ch];     // rows [32,64)
        float Ac = s1.x * s0.x;
        float Vc = fmaf(s1.x, s0.y, s1.y);
        const int b   = bm >> 5;                 // 4096/128 = 32 row-blocks/batch
        const int ckg = (bm & 31) * 2 + ck;      // global chunk in [0,64)
        const size_t idx = ((size_t)(b * 64 + ckg)) * 512 + bn * 64 + ch;
        cA[idx] = Ac;
        cV[idx] = Vc;
    }
}

// ---------------------------------------------------------------------------
// pass2: sequential combine across 64 chunks per batch. 2 channels/thread.
// ---------------------------------------------------------------------------
__global__ __launch_bounds__(256) void scan_pass2(
    const float* __restrict__ cA, const float* __restrict__ cV,
    float* __restrict__ carry, int Nc)
{
    const int tid = threadIdx.x;
    const int b = blockIdx.x;
    float s0 = 0.5f, s1 = 0.5f;   // h0
    #pragma unroll 8
    for (int ck = 0; ck < Nc; ++ck) {
        const size_t idx = (size_t)(b * Nc + ck) * 512 + 2 * tid;
        *(float2*)(carry + idx) = make_float2(s0, s1);
        float2 a = *(const float2*)(cA + idx);
        float2 v = *(const float2*)(cV + idx);
        s0 = fmaf(a.x, s0, v.x);
        s1 = fmaf(a.y, s1, v.y);
    }
}

// ---------------------------------------------------------------------------
// pass3: replay each chunk from its carry, write all h_t (+ last-step h).
// ---------------------------------------------------------------------------
template <bool OUT_BF16>
__global__ __launch_bounds__(256) void scan_pass3(
    const u16* __restrict__ gh, const float* __restrict__ carry,
    void* __restrict__ outv, float* __restrict__ nh,
    int S, int Lc, int Nc)
{
    const int tid = threadIdx.x;
    const int b  = blockIdx.x / Nc;
    const int ck = blockIdx.x % Nc;
    const u16* base = gh + (size_t)(b * S + ck * Lc) * 1024 + 2 * tid;
    const size_t cidx = (size_t)(b * Nc + ck) * 512 + 2 * tid;
    float2 st = *(const float2*)(carry + cidx);
    float h0 = st.x, h1 = st.y;
    const size_t obase = (size_t)(b * S + ck * Lc) * 512 + 2 * tid;
    #pragma unroll 4
    for (int s = 0; s < Lc; ++s) {
        ushort2 g2 = *(const ushort2*)(base + (size_t)s * 1024);
        ushort2 h2 = *(const ushort2*)(base + (size_t)s * 1024 + 512);
        float c0, v0, c1, v1;
        coeff_val(bf2f(g2.x), bf2f(h2.x), c0, v0);
        coeff_val(bf2f(g2.y), bf2f(h2.y), c1, v1);
        h0 = fmaf(c0, h0, v0);
        h1 = fmaf(c1, h1, v1);
        if (OUT_BF16) {
            ushort2 o = make_ushort2(f2bf(h0), f2bf(h1));
            *(ushort2*)((u16*)outv + obase + (size_t)s * 512) = o;
        } else {
            *(float2*)((float*)outv + obase + (size_t)s * 512) = make_float2(h0, h1);
        }
    }
    if (ck == Nc - 1)
        *(float2*)(nh + (size_t)b * 512 + 2 * tid) = make_float2(h0, h1);
}

// ---------------------------------------------------------------------------
extern "C" void kernel_launch(void* const* d_in, const int* in_sizes, int n_in,
                              void* d_out, int out_size, void* d_ws, size_t ws_size,
                              hipStream_t stream)
{
    const float* x  = (const float*)d_in[0];
    const float* w0 = (const float*)d_in[1];
    const float* b0 = (const float*)d_in[2];
    const float* w1 = (const float*)d_in[3];
    const float* b1 = (const float*)d_in[4];
    float* out = (float*)d_out;

    const int B = 8, S = 4096, K = 512;
    const int M = B * S;             // 32768
    const int Lc = 64, Nc = S / Lc;  // 64 chunks of 64

    // workspace (bf16 elems): gh M*1024, xb M*512, h0b M*512, w0b/w1b 1024*512
    u16* gh  = (u16*)d_ws;
    u16* xb  = gh  + (size_t)M * 1024;
    u16* h0b = xb  + (size_t)M * 512;
    u16* w0b = h0b + (size_t)M * 512;
    u16* w1b = w0b + (size_t)1024 * 512;
    float* cA    = (float*)(w1b + (size_t)1024 * 512);
    float* cV    = cA + (size_t)B * Nc * 512;
    float* carry = cV + (size_t)B * Nc * 512;

    float* nh0 = out + (size_t)M * 512;
    float* nh1 = nh0 + (size_t)B * 512;

    dim3 blk(256);
    dim3 ggrid(8, M / 128);          // 8 channel-blocks x 256 row-blocks
    dim3 sgrid(B * Nc);              // 512

    const int nx4 = M * K / 4;           // 4,194,304
    const int nw4 = 1024 * K / 4;        // 131,072
    cast3<<<dim3((nx4 + 2 * nw4 + 255) / 256), blk, 0, stream>>>(
        x, xb, nx4, w0, w0b, w1, w1b, nw4);

    // ---- layer 0 ----
    gemm_fused<<<ggrid, blk, 0, stream>>>(xb, w0b, b0, gh, cA, cV, K);
    scan_pass2<<<dim3(B), blk, 0, stream>>>(cA, cV, carry, Nc);
    scan_pass3<true><<<sgrid, blk, 0, stream>>>(gh, carry, h0b, nh0, S, Lc, Nc);

    // ---- layer 1 ----
    gemm_fused<<<ggrid, blk, 0, stream>>>(h0b, w1b, b1, gh, cA, cV, K);
    scan_pass2<<<dim3(B), blk, 0, stream>>>(cA, cV, carry, Nc);
    scan_pass3<false><<<sgrid, blk, 0, stream>>>(gh, carry, out, nh1, S, Lc, Nc);
}